// Round 1
// baseline (653.311 us; speedup 1.0000x reference)
//
#include <hip/hip_runtime.h>

#define Bb 4
#define Nn 20000
#define Ee 320000
#define CIN 32
#define COUT 32
#define Kk 16
#define Mm 2

// ---------------- kernel 1: transpose f (B,CIN,N) -> fT (B,N,CIN); zero f_out
__global__ __launch_bounds__(256) void prep_kernel(const float* __restrict__ f,
                                                   float* __restrict__ fT,
                                                   float* __restrict__ f_out) {
    __shared__ float lds[32 * 33];
    int blk  = blockIdx.x;
    int b    = blk / 625;        // N/32 = 625 tiles per batch
    int tile = blk % 625;
    int n0   = tile * 32;
    int t    = threadIdx.x;
    int lane = t & 31;
    int grp  = t >> 5;           // 0..7
    #pragma unroll
    for (int r = 0; r < 4; ++r) {
        int i = grp + r * 8;
        int n = n0 + lane;
        lds[i * 33 + lane] = f[(b * CIN + i) * Nn + n];
        f_out[(b * Nn + n0) * CIN + r * 256 + t] = 0.0f;
    }
    __syncthreads();
    #pragma unroll
    for (int r = 0; r < 4; ++r) {
        int nl = grp + r * 8;
        fT[(b * Nn + n0 + nl) * CIN + lane] = lds[lane * 33 + nl];
    }
}

// ---------------- kernel 2: edge scatter
// one 32-lane half-wave per edge-instance; lane = output channel
__global__ __launch_bounds__(256) void edge_kernel(
    const float* __restrict__ fT,
    const float* __restrict__ bases_c,
    const float* __restrict__ bases_s,
    const float* __restrict__ nodes,
    const float* __restrict__ nrm,
    const int*   __restrict__ de,
    const float* __restrict__ nwt,
    const float* __restrict__ wc,
    const float* __restrict__ wsp,
    const float* __restrict__ w0,
    float* __restrict__ f_out) {
    const int tid    = blockIdx.x * 256 + threadIdx.x;
    const int g0     = tid >> 5;                 // group id = instance id start
    const int li     = threadIdx.x & 31;         // channel 0..31
    const int laneid = threadIdx.x & 63;
    const int sbase  = laneid & 32;              // shuffle base of this half-wave
    const int k16    = li & 15;
    const int half   = li >> 4;
    const int S      = (gridDim.x * 256) >> 5;   // group stride (even)
    const int TOT    = Bb * Ee * Mm;             // 2,560,000 instances

    // m = instance parity; S is even so it is loop-invariant
    const int m = g0 & 1;

    // preload weight row for (channel li, measure m); fold the 2.0f in
    float wcr[16], wsr[16];
    #pragma unroll
    for (int k = 0; k < 16; ++k) {
        wcr[k] = 2.0f * wc[(li * Kk + k) * Mm + m];
        wsr[k] = 2.0f * wsp[(li * Kk + k) * Mm + m];
    }
    const float acc0 = w0[li * Mm + m] + 1.0f;   // (edge_w + 1) folded

    const float* arr = half ? bases_s : bases_c;

    for (int g = g0; g < TOT; g += S) {
        unsigned eb = (unsigned)(g >> 1);
        int b = (int)(eb / (unsigned)Ee);
        int e = (int)(eb - (unsigned)b * (unsigned)Ee);
        int ebase = ((b * Ee + e) * 2) * Mm + m;
        int tnode = de[ebase];          // target
        int snode = de[ebase + Mm];     // source

        int bt = b * Nn + tnode;
        int bs = b * Nn + snode;

        float2 nt = *(const float2*)(nodes + bt * 2);
        float2 ns = *(const float2*)(nodes + bs * 2);
        float2 nv = *(const float2*)(nrm + bs * 2);
        float dx = nt.x - ns.x, dy = nt.y - ns.y;
        float r2 = dx * dx + dy * dy + 1e-6f;
        float gr = (dx * nv.x + dy * nv.y) / r2;
        float scale = nwt[(b * Ee + e) * Mm + m] * gr;

        // lanes 0-15: a=bc_t, as=bc_s ; lanes 16-31: a=bs_t, as=bs_s
        float at = arr[(bt * Kk + k16) * Mm + m];
        float as = arr[(bs * Kk + k16) * Mm + m];
        float pt = __shfl_xor(at, 16);
        float ps = __shfl_xor(as, 16);
        // lanes<16 hold cc[k] = bc_t*bc_s + bs_t*bs_s
        // lanes>=16 hold ss[k] = bc_t*bs_s - bs_t*bc_s
        float v = half ? (pt * as - at * ps) : (at * as + pt * ps);

        float acc = acc0;
        #pragma unroll
        for (int k = 0; k < 16; ++k) {
            float ck = __shfl(v, sbase + k);
            float sk = __shfl(v, sbase + 16 + k);
            acc += wcr[k] * ck + wsr[k] * sk;
        }

        float fs = fT[bs * CIN + li];
        unsafeAtomicAdd(&f_out[bt * CIN + li], acc * fs * scale);
    }
}

// ---------------- kernel 3: out[b,o,n] = bias[o] + sum_i wk[o,i] * f_out[b,n,i]
__global__ __launch_bounds__(256) void out_kernel(
    const float* __restrict__ f_out,
    const float* __restrict__ wk,
    const float* __restrict__ bias,
    float* __restrict__ out) {
    __shared__ float lwk[1024];
    __shared__ float lf[64 * 33];
    int blk  = blockIdx.x;
    int b    = blk / 313;
    int tile = blk % 313;
    int n0   = tile * 64;
    int t    = threadIdx.x;
    #pragma unroll
    for (int r = 0; r < 4; ++r) lwk[r * 256 + t] = wk[r * 256 + t];
    #pragma unroll
    for (int r = 0; r < 8; ++r) {
        int flat = r * 256 + t;       // 0..2047
        int nl   = flat >> 5;
        int i    = flat & 31;
        int n    = n0 + nl;
        lf[nl * 33 + i] = (n < Nn) ? f_out[(b * Nn + n) * CIN + i] : 0.0f;
    }
    __syncthreads();
    int nl = t & 63;
    int og = t >> 6;                   // 0..3
    int n  = n0 + nl;
    if (n < Nn) {
        #pragma unroll
        for (int r = 0; r < 8; ++r) {
            int o = r * 4 + og;
            float acc = bias[o];
            #pragma unroll
            for (int i = 0; i < 32; ++i) acc += lwk[o * 32 + i] * lf[nl * 33 + i];
            out[(b * COUT + o) * Nn + n] = acc;
        }
    }
}

extern "C" void kernel_launch(void* const* d_in, const int* in_sizes, int n_in,
                              void* d_out, int out_size, void* d_ws, size_t ws_size,
                              hipStream_t stream) {
    const float* f       = (const float*)d_in[0];
    const float* bases_c = (const float*)d_in[1];
    const float* bases_s = (const float*)d_in[2];
    // d_in[3] = bases_0 (unused by reference)
    const float* nodes   = (const float*)d_in[4];
    const float* nrm     = (const float*)d_in[5];
    const int*   de      = (const int*)d_in[6];
    const float* nwt     = (const float*)d_in[7];
    const float* wc      = (const float*)d_in[8];
    const float* wsp     = (const float*)d_in[9];
    const float* w0      = (const float*)d_in[10];
    const float* wk      = (const float*)d_in[11];
    const float* bias    = (const float*)d_in[12];
    float* out = (float*)d_out;

    float* fT    = (float*)d_ws;                 // B*N*CIN floats = 10.24 MB
    float* f_out = fT + (size_t)Bb * Nn * CIN;   // B*N*CIN floats = 10.24 MB

    prep_kernel<<<Bb * 625, 256, 0, stream>>>(f, fT, f_out);
    edge_kernel<<<2048, 256, 0, stream>>>(fT, bases_c, bases_s, nodes, nrm, de,
                                          nwt, wc, wsp, w0, f_out);
    out_kernel<<<Bb * 313, 256, 0, stream>>>(f_out, wk, bias, out);
}

// Round 2
// 495.626 us; speedup vs baseline: 1.3182x; 1.3182x over previous
//
#include <hip/hip_runtime.h>

#define Bb 4
#define Nn 20000
#define Ee 320000
#define CIN 32
#define COUT 32
#define Kk 16
#define Mm 2
#define TOT (Bb * Ee * Mm)      /* 2,560,000 edge-instances */
#define NGRP 16384              /* 2048 blocks * 8 groups */

// ---------------- kernel 1: transpose f (B,CIN,N) -> fT (B,N,CIN); zero f_out
__global__ __launch_bounds__(256) void prep_kernel(const float* __restrict__ f,
                                                   float* __restrict__ fT,
                                                   float* __restrict__ f_out) {
    __shared__ float lds[32 * 33];
    int blk  = blockIdx.x;
    int b    = blk / 625;
    int tile = blk % 625;
    int n0   = tile * 32;
    int t    = threadIdx.x;
    int lane = t & 31;
    int grp  = t >> 5;
    #pragma unroll
    for (int r = 0; r < 4; ++r) {
        int i = grp + r * 8;
        int n = n0 + lane;
        lds[i * 33 + lane] = f[(b * CIN + i) * Nn + n];
        f_out[(b * Nn + n0) * CIN + r * 256 + t] = 0.0f;
    }
    __syncthreads();
    #pragma unroll
    for (int r = 0; r < 4; ++r) {
        int nl = grp + r * 8;
        fT[(b * Nn + n0 + nl) * CIN + lane] = lds[lane * 33 + nl];
    }
}

// ---------------- kernel 1b: pack bases -> pb[b][m][n][32] (bc||bs), nodes+nrm -> pn float4
__global__ __launch_bounds__(256) void pack_kernel(const float* __restrict__ bases_c,
                                                   const float* __restrict__ bases_s,
                                                   const float* __restrict__ nodes,
                                                   const float* __restrict__ nrm,
                                                   float* __restrict__ pb,
                                                   float4* __restrict__ pn) {
    int t0 = blockIdx.x * 256 + threadIdx.x;
    int S  = gridDim.x * 256;
    for (int i = t0; i < Bb * Mm * Nn * 32; i += S) {
        int j  = i & 31;
        int nn = (i >> 5) % Nn;
        int bm = (i >> 5) / Nn;          // b*2 + m
        int m  = bm & 1, b = bm >> 1;
        int k  = j & 15;
        const float* src = (j < 16) ? bases_c : bases_s;
        pb[i] = src[((b * Nn + nn) * Kk + k) * Mm + m];
    }
    for (int i = t0; i < Bb * Nn; i += S) {
        float2 nd = ((const float2*)nodes)[i];
        float2 nv = ((const float2*)nrm)[i];
        pn[i] = make_float4(nd.x, nd.y, nv.x, nv.y);
    }
}

// ---------------- kernel 2: edge scatter (32-lane group per edge-instance, lane = channel)
__global__ __launch_bounds__(256) void edge_kernel(
    const float* __restrict__ pb,
    const float4* __restrict__ pn,
    const float* __restrict__ fT,
    const int4* __restrict__ de4,
    const float* __restrict__ nwt,
    const float* __restrict__ wc,
    const float* __restrict__ wsp,
    const float* __restrict__ w0,
    float* __restrict__ f_out) {
    __shared__ __align__(16) float vbuf[8][2][32];
    const int t    = threadIdx.x;
    const int li   = t & 31;
    const int grp  = t >> 5;
    const int g0   = blockIdx.x * 8 + grp;
    const int m    = g0 & 1;               // NGRP even -> loop-invariant
    const int half = li >> 4;

    // weight row for (channel li, measure m): [2*wc | 2*ws]
    float wfull[32];
    #pragma unroll
    for (int k = 0; k < 16; ++k) {
        wfull[k]      = 2.0f * wc [(li * Kk + k) * Mm + m];
        wfull[16 + k] = 2.0f * wsp[(li * Kk + k) * Mm + m];
    }
    const float acc0 = w0[li * Mm + m] + 1.0f;

    int g = g0;
    for (; g + NGRP < TOT; g += 2 * NGRP) {
        int   bt[2], bs[2];
        float scale[2], at[2], as[2], fs[2];
        #pragma unroll
        for (int u = 0; u < 2; ++u) {
            int gi = g + u * NGRP;
            unsigned eb = (unsigned)(gi >> 1);
            int b = (int)(eb / (unsigned)Ee);
            int e = (int)(eb - (unsigned)b * (unsigned)Ee);
            int4 d4 = de4[b * Ee + e];          // (t_m0, t_m1, s_m0, s_m1)
            int tn = m ? d4.y : d4.x;
            int sn = m ? d4.w : d4.z;
            bt[u] = b * Nn + tn;
            bs[u] = b * Nn + sn;
            float4 qt = pn[bt[u]];
            float4 qs = pn[bs[u]];
            float dx = qt.x - qs.x, dy = qt.y - qs.y;
            float r2 = dx * dx + dy * dy + 1e-6f;
            float gr = (dx * qs.z + dy * qs.w) / r2;
            scale[u] = nwt[(b * Ee + e) * Mm + m] * gr;
            at[u] = pb[(((b << 1) | m) * Nn + tn) * 32 + li];
            as[u] = pb[(((b << 1) | m) * Nn + sn) * 32 + li];
            fs[u] = fT[bs[u] * CIN + li];
        }
        #pragma unroll
        for (int u = 0; u < 2; ++u) {
            float pt = __shfl_xor(at[u], 16);
            float ps = __shfl_xor(as[u], 16);
            // lanes<16: cc[k], lanes>=16: ss[k]
            float v = half ? (pt * as[u] - at[u] * ps) : (at[u] * as[u] + pt * ps);
            vbuf[grp][u][li] = v;
        }
        #pragma unroll
        for (int u = 0; u < 2; ++u) {
            const float4* vv = (const float4*)(vbuf[grp][u]);
            float acc = acc0;
            #pragma unroll
            for (int q = 0; q < 8; ++q) {
                float4 c = vv[q];
                acc += wfull[4 * q]     * c.x + wfull[4 * q + 1] * c.y +
                       wfull[4 * q + 2] * c.z + wfull[4 * q + 3] * c.w;
            }
            unsafeAtomicAdd(&f_out[bt[u] * CIN + li], acc * fs[u] * scale[u]);
        }
    }
    if (g < TOT) {  // tail: one remaining instance
        unsigned eb = (unsigned)(g >> 1);
        int b = (int)(eb / (unsigned)Ee);
        int e = (int)(eb - (unsigned)b * (unsigned)Ee);
        int4 d4 = de4[b * Ee + e];
        int tn = m ? d4.y : d4.x;
        int sn = m ? d4.w : d4.z;
        int bt = b * Nn + tn, bs = b * Nn + sn;
        float4 qt = pn[bt];
        float4 qs = pn[bs];
        float dx = qt.x - qs.x, dy = qt.y - qs.y;
        float r2 = dx * dx + dy * dy + 1e-6f;
        float gr = (dx * qs.z + dy * qs.w) / r2;
        float scale = nwt[(b * Ee + e) * Mm + m] * gr;
        float at = pb[(((b << 1) | m) * Nn + tn) * 32 + li];
        float as = pb[(((b << 1) | m) * Nn + sn) * 32 + li];
        float fs = fT[bs * CIN + li];
        float pt = __shfl_xor(at, 16);
        float ps = __shfl_xor(as, 16);
        float v = half ? (pt * as - at * ps) : (at * as + pt * ps);
        vbuf[grp][0][li] = v;
        const float4* vv = (const float4*)(vbuf[grp][0]);
        float acc = acc0;
        #pragma unroll
        for (int q = 0; q < 8; ++q) {
            float4 c = vv[q];
            acc += wfull[4 * q]     * c.x + wfull[4 * q + 1] * c.y +
                   wfull[4 * q + 2] * c.z + wfull[4 * q + 3] * c.w;
        }
        unsafeAtomicAdd(&f_out[bt * CIN + li], acc * fs * scale);
    }
}

// ---------------- kernel 3: out[b,o,n] = bias[o] + sum_i wk[o,i] * f_out[b,n,i]
__global__ __launch_bounds__(256) void out_kernel(
    const float* __restrict__ f_out,
    const float* __restrict__ wk,
    const float* __restrict__ bias,
    float* __restrict__ out) {
    __shared__ float lwk[1024];
    __shared__ float lf[64 * 33];
    int blk  = blockIdx.x;
    int b    = blk / 313;
    int tile = blk % 313;
    int n0   = tile * 64;
    int t    = threadIdx.x;
    #pragma unroll
    for (int r = 0; r < 4; ++r) lwk[r * 256 + t] = wk[r * 256 + t];
    #pragma unroll
    for (int r = 0; r < 8; ++r) {
        int flat = r * 256 + t;
        int nl   = flat >> 5;
        int i    = flat & 31;
        int n    = n0 + nl;
        lf[nl * 33 + i] = (n < Nn) ? f_out[(b * Nn + n) * CIN + i] : 0.0f;
    }
    __syncthreads();
    int nl = t & 63;
    int og = t >> 6;
    int n  = n0 + nl;
    if (n < Nn) {
        #pragma unroll
        for (int r = 0; r < 8; ++r) {
            int o = r * 4 + og;
            float acc = bias[o];
            #pragma unroll
            for (int i = 0; i < 32; ++i) acc += lwk[o * 32 + i] * lf[nl * 33 + i];
            out[(b * COUT + o) * Nn + n] = acc;
        }
    }
}

extern "C" void kernel_launch(void* const* d_in, const int* in_sizes, int n_in,
                              void* d_out, int out_size, void* d_ws, size_t ws_size,
                              hipStream_t stream) {
    const float* f       = (const float*)d_in[0];
    const float* bases_c = (const float*)d_in[1];
    const float* bases_s = (const float*)d_in[2];
    const float* nodes   = (const float*)d_in[4];
    const float* nrm     = (const float*)d_in[5];
    const int*   de      = (const int*)d_in[6];
    const float* nwt     = (const float*)d_in[7];
    const float* wc      = (const float*)d_in[8];
    const float* wsp     = (const float*)d_in[9];
    const float* w0      = (const float*)d_in[10];
    const float* wk      = (const float*)d_in[11];
    const float* bias    = (const float*)d_in[12];
    float* out = (float*)d_out;

    float*  fT    = (float*)d_ws;                        // 2.56M floats
    float*  f_out = fT + (size_t)Bb * Nn * CIN;          // 2.56M floats
    float*  pb    = f_out + (size_t)Bb * Nn * CIN;       // 5.12M floats
    float4* pn    = (float4*)(pb + (size_t)Bb * Mm * Nn * 32); // 80k float4

    prep_kernel<<<Bb * 625, 256, 0, stream>>>(f, fT, f_out);
    pack_kernel<<<1024, 256, 0, stream>>>(bases_c, bases_s, nodes, nrm, pb, pn);
    edge_kernel<<<2048, 256, 0, stream>>>(pb, pn, fT, (const int4*)de, nwt,
                                          wc, wsp, w0, f_out);
    out_kernel<<<Bb * 313, 256, 0, stream>>>(f_out, wk, bias, out);
}

// Round 3
// 429.148 us; speedup vs baseline: 1.5223x; 1.1549x over previous
//
#include <hip/hip_runtime.h>

#define Bb 4
#define Nn 20000
#define Ee 320000
#define CIN 32
#define COUT 32
#define Kk 16
#define Mm 2
#define TOT (Bb * Ee * Mm)          /* 2,560,000 edge-instances */
#define NTILE (TOT / 16)            /* 160,000 tiles of 16 instances */
#define NWAVE 8192                  /* 2048 blocks * 4 waves; even -> m uniform */

typedef __attribute__((ext_vector_type(8))) short short8;
typedef __attribute__((ext_vector_type(4))) float f32x4;

__device__ __forceinline__ unsigned f2bf(float x) {   // round-half-up bf16 bits
    union { float f; unsigned u; } c; c.f = x;
    return (c.u + 0x8000u) >> 16;
}

// ---------------- kernel 1: fused prep
//  phase A: transpose f (B,CIN,N) -> fT (B,N,CIN)  [2500 tile-blocks]
//  phase B: zero f_out; pack pb[b][m][node][32] = [bc(k=0..15) | bs(k=0..15)];
//           pack pn = (node.x, node.y, nv.x, nv.y)
__global__ __launch_bounds__(256) void prep_fused(
    const float* __restrict__ f,
    const float* __restrict__ bases_c,
    const float* __restrict__ bases_s,
    const float* __restrict__ nodes,
    const float* __restrict__ nrm,
    float* __restrict__ fT,
    float* __restrict__ f_out,
    float* __restrict__ pb,
    float4* __restrict__ pn) {
    __shared__ float lds[32 * 33];
    const int t = threadIdx.x;
    // phase A: each block < 2500 does one 32x32 transpose tile
    for (int blk = blockIdx.x; blk < Bb * 625; blk += gridDim.x) {
        int b = blk / 625, tile = blk % 625;
        int n0 = tile * 32;
        int lane = t & 31, grp = t >> 5;
        #pragma unroll
        for (int r = 0; r < 4; ++r)
            lds[(grp + r * 8) * 33 + lane] = f[(b * CIN + grp + r * 8) * Nn + n0 + lane];
        __syncthreads();
        #pragma unroll
        for (int r = 0; r < 4; ++r)
            fT[(b * Nn + n0 + grp + r * 8) * CIN + lane] = lds[lane * 33 + grp + r * 8];
        __syncthreads();
    }
    const int t0 = blockIdx.x * 256 + t;
    const int S  = gridDim.x * 256;
    for (int i = t0; i < Bb * Nn * CIN; i += S) f_out[i] = 0.0f;
    for (int i = t0; i < Bb * Mm * Nn * 32; i += S) {
        int j  = i & 31;
        int nn = (i >> 5) % Nn;
        int bm = (i >> 5) / Nn;
        int m  = bm & 1, b = bm >> 1;
        int k  = j & 15;
        const float* src = (j < 16) ? bases_c : bases_s;
        pb[i] = src[((b * Nn + nn) * Kk + k) * Mm + m];
    }
    for (int i = t0; i < Bb * Nn; i += S) {
        float2 nd = ((const float2*)nodes)[i];
        float2 nv = ((const float2*)nrm)[i];
        pn[i] = make_float4(nd.x, nd.y, nv.x, nv.y);
    }
}

// ---------------- kernel 2: edge scatter, MFMA matvec
// wave = 64 lanes handles 16 edge-instances (same b, same m) per iteration.
// lane l: c = l&15, q = l>>4. Geometry computed for inst c (4-way redundant).
// A-frag (verified m120): A[inst=l&15][k=q*8+j] ; V[k<16]=cc[k], V[k>=16]=ss[k-16]
// B-frag (symmetric):     B[k=q*8+j][ch=l&15]   ; D[inst][ch], 2 MFMAs for 32 ch
// C/D (verified m89/m91): lane holds ch=l&15, inst=q*4+reg
__global__ __launch_bounds__(256, 4) void edge_kernel(
    const float* __restrict__ pb,
    const float4* __restrict__ pn,
    const float* __restrict__ fT,
    const int4* __restrict__ de4,
    const float* __restrict__ nwt,
    const float* __restrict__ wc,
    const float* __restrict__ wsp,
    const float* __restrict__ w0,
    float* __restrict__ f_out) {
    const int t  = threadIdx.x;
    const int wv = t >> 6;
    const int l  = t & 63;
    const int c  = l & 15;
    const int q  = l >> 4;
    const int kb = (q & 1) * 8;          // k offset within the 16-dim half
    const int mode = q >> 1;             // 0: cc lanes, 1: ss lanes
    const unsigned smask = mode ? 0x80000000u : 0u;
    const int T0 = blockIdx.x * 4 + wv;
    const int m  = T0 & 1;               // NWAVE even -> loop-invariant

    // loop-invariant B fragments (weights, bf16)
    short8 bf0, bf1;
    #pragma unroll
    for (int j = 0; j < 8; ++j) {
        int k = q * 8 + j;
        float w0v, w1v;
        if (k < 16) {
            w0v = 2.0f * wc[(c * Kk + k) * Mm + m];
            w1v = 2.0f * wc[((c + 16) * Kk + k) * Mm + m];
        } else {
            w0v = 2.0f * wsp[(c * Kk + (k - 16)) * Mm + m];
            w1v = 2.0f * wsp[((c + 16) * Kk + (k - 16)) * Mm + m];
        }
        bf0[j] = (short)f2bf(w0v);
        bf1[j] = (short)f2bf(w1v);
    }
    const float acc00 = w0[c * Mm + m] + 1.0f;
    const float acc01 = w0[(c + 16) * Mm + m] + 1.0f;

    for (int T = T0; T < NTILE; T += NWAVE) {
        int ebt = (T >> 1) * 16;         // first (b,e) of tile; Ee%16==0 -> b uniform
        int b   = ebt / Ee;
        int e   = (ebt - b * Ee) + c;    // my inst = c (4-way redundant over q)
        int4 d4 = de4[b * Ee + e];       // (t_m0, t_m1, s_m0, s_m1)
        int tn = m ? d4.y : d4.x;
        int sn = m ? d4.w : d4.z;
        int bt = b * Nn + tn;
        int bs = b * Nn + sn;
        float4 qt = pn[bt];
        float4 qs = pn[bs];
        float dx = qt.x - qs.x, dy = qt.y - qs.y;
        float r2 = dx * dx + dy * dy + 1e-6f;
        float scale = nwt[(b * Ee + e) * Mm + m] * (dx * qs.z + dy * qs.w) / r2;

        // pb gathers: t-node plain; s-node with mode-swapped halves
        const float* pt_ = pb + ((size_t)((b * 2 + m) * Nn + tn)) * 32 + kb;
        const float* ps_ = pb + ((size_t)((b * 2 + m) * Nn + sn)) * 32 + kb;
        const float* px  = ps_ + (mode ? 16 : 0);   // x: bcs (cc) / bss (ss)
        const float* py  = ps_ + (mode ? 0 : 16);   // y: bss (cc) / bcs (ss)
        float bct[8], bst[8], xx[8], yy[8];
        *(float4*)(bct)     = *(const float4*)(pt_);
        *(float4*)(bct + 4) = *(const float4*)(pt_ + 4);
        *(float4*)(bst)     = *(const float4*)(pt_ + 16);
        *(float4*)(bst + 4) = *(const float4*)(pt_ + 20);
        *(float4*)(xx)      = *(const float4*)(px);
        *(float4*)(xx + 4)  = *(const float4*)(px + 4);
        *(float4*)(yy)      = *(const float4*)(py);
        *(float4*)(yy + 4)  = *(const float4*)(py + 4);

        // v[j] = bct*x + (mode? -bst : bst)*y  ->  cc (mode 0) / ss (mode 1)
        union { short8 s8; unsigned u[4]; } af;
        #pragma unroll
        for (int jj = 0; jj < 4; ++jj) {
            float s0 = __uint_as_float(__float_as_uint(bst[2 * jj])     ^ smask);
            float s1 = __uint_as_float(__float_as_uint(bst[2 * jj + 1]) ^ smask);
            float v0 = fmaf(bct[2 * jj],     xx[2 * jj],     s0 * yy[2 * jj]);
            float v1 = fmaf(bct[2 * jj + 1], xx[2 * jj + 1], s1 * yy[2 * jj + 1]);
            af.u[jj] = f2bf(v0) | ((__float_as_uint(v1) + 0x8000u) & 0xffff0000u);
        }

        f32x4 zero = {0.f, 0.f, 0.f, 0.f};
        f32x4 d0 = __builtin_amdgcn_mfma_f32_16x16x32_bf16(af.s8, bf0, zero, 0, 0, 0);
        f32x4 d1 = __builtin_amdgcn_mfma_f32_16x16x32_bf16(af.s8, bf1, zero, 0, 0, 0);

        // epilogue: lane holds (inst = 4q+r, ch = c and c+16)
        #pragma unroll
        for (int r = 0; r < 4; ++r) {
            int   src = 4 * q + r;
            float sc  = __shfl(scale, src);
            int   btr = __shfl(bt, src);
            int   bsr = __shfl(bs, src);
            float fs0 = fT[bsr * CIN + c];
            float fs1 = fT[bsr * CIN + c + 16];
            unsafeAtomicAdd(&f_out[btr * CIN + c],      (acc00 + d0[r]) * fs0 * sc);
            unsafeAtomicAdd(&f_out[btr * CIN + c + 16], (acc01 + d1[r]) * fs1 * sc);
        }
    }
}

// ---------------- kernel 3: out[b,o,n] = bias[o] + sum_i wk[o,i] * f_out[b,n,i]
__global__ __launch_bounds__(256) void out_kernel(
    const float* __restrict__ f_out,
    const float* __restrict__ wk,
    const float* __restrict__ bias,
    float* __restrict__ out) {
    __shared__ float lwk[1024];
    __shared__ float lf[64 * 33];
    int blk  = blockIdx.x;
    int b    = blk / 313;
    int tile = blk % 313;
    int n0   = tile * 64;
    int t    = threadIdx.x;
    #pragma unroll
    for (int r = 0; r < 4; ++r) lwk[r * 256 + t] = wk[r * 256 + t];
    #pragma unroll
    for (int r = 0; r < 8; ++r) {
        int flat = r * 256 + t;
        int nl   = flat >> 5;
        int i    = flat & 31;
        int n    = n0 + nl;
        lf[nl * 33 + i] = (n < Nn) ? f_out[(b * Nn + n) * CIN + i] : 0.0f;
    }
    __syncthreads();
    int nl = t & 63;
    int og = t >> 6;
    int n  = n0 + nl;
    if (n < Nn) {
        #pragma unroll
        for (int r = 0; r < 8; ++r) {
            int o = r * 4 + og;
            float acc = bias[o];
            #pragma unroll
            for (int i = 0; i < 32; ++i) acc += lwk[o * 32 + i] * lf[nl * 33 + i];
            out[(b * COUT + o) * Nn + n] = acc;
        }
    }
}

extern "C" void kernel_launch(void* const* d_in, const int* in_sizes, int n_in,
                              void* d_out, int out_size, void* d_ws, size_t ws_size,
                              hipStream_t stream) {
    const float* f       = (const float*)d_in[0];
    const float* bases_c = (const float*)d_in[1];
    const float* bases_s = (const float*)d_in[2];
    const float* nodes   = (const float*)d_in[4];
    const float* nrm     = (const float*)d_in[5];
    const int*   de      = (const int*)d_in[6];
    const float* nwt     = (const float*)d_in[7];
    const float* wc      = (const float*)d_in[8];
    const float* wsp     = (const float*)d_in[9];
    const float* w0      = (const float*)d_in[10];
    const float* wk      = (const float*)d_in[11];
    const float* bias    = (const float*)d_in[12];
    float* out = (float*)d_out;

    float*  fT    = (float*)d_ws;                              // 2.56M floats
    float*  f_out = fT + (size_t)Bb * Nn * CIN;                // 2.56M floats
    float*  pb    = f_out + (size_t)Bb * Nn * CIN;             // 5.12M floats
    float4* pn    = (float4*)(pb + (size_t)Bb * Mm * Nn * 32); // 80k float4

    prep_fused<<<Bb * 625, 256, 0, stream>>>(f, bases_c, bases_s, nodes, nrm,
                                             fT, f_out, pb, pn);
    edge_kernel<<<2048, 256, 0, stream>>>(pb, pn, fT, (const int4*)de, nwt,
                                          wc, wsp, w0, f_out);
    out_kernel<<<Bb * 313, 256, 0, stream>>>(f_out, wk, bias, out);
}

// Round 4
// 393.822 us; speedup vs baseline: 1.6589x; 1.0897x over previous
//
#include <hip/hip_runtime.h>

#define Bb 4
#define Nn 20000
#define Ee 320000
#define CIN 32
#define COUT 32
#define Kk 16
#define Mm 2
#define EPB (Ee / 64)   /* 5000 super-iters (64 instances) per (b,m) slice */
#define WPB 1024        /* waves per (b,m): (2048/8) blocks * 4 waves */

typedef __attribute__((ext_vector_type(8))) short short8;
typedef __attribute__((ext_vector_type(4))) float f32x4;

__device__ __forceinline__ unsigned f2bf(float x) {   // round-half-up bf16 bits
    union { float f; unsigned u; } c; c.f = x;
    return (c.u + 0x8000u) >> 16;
}

// ---------------- kernel 1: fused prep
//  A: transpose f (B,CIN,N) -> fT (B,N,CIN)      [one 32-node tile per block]
//  C: pack pb[b][m][node][32] = [bc k=0..15 | bs k=0..15] via LDS deinterleave
//  B/D: zero f_out (float4); pack pn = (node.xy, nv.xy)
__global__ __launch_bounds__(256) void prep_fused(
    const float* __restrict__ f,
    const float4* __restrict__ bc4,
    const float4* __restrict__ bs4,
    const float* __restrict__ nodes,
    const float* __restrict__ nrm,
    float* __restrict__ fT,
    float4* __restrict__ f_out4,
    float* __restrict__ pb,
    float4* __restrict__ pn) {
    __shared__ float ldsT[32 * 33];
    __shared__ float ldc[32 * 33];
    __shared__ float ldss[32 * 33];
    const int t   = threadIdx.x;
    const int blk = blockIdx.x;            // 2500 blocks
    const int b   = blk / 625;
    const int n0  = (blk % 625) * 32;
    // phase A: 32x32 transpose tile
    {
        int lane = t & 31, grp = t >> 5;
        #pragma unroll
        for (int r = 0; r < 4; ++r)
            ldsT[(grp + r * 8) * 33 + lane] = f[(b * CIN + grp + r * 8) * Nn + n0 + lane];
        __syncthreads();
        #pragma unroll
        for (int r = 0; r < 4; ++r)
            fT[(b * Nn + n0 + grp + r * 8) * CIN + lane] = ldsT[lane * 33 + grp + r * 8];
    }
    // phase C: pack 32 nodes (fully coalesced in and out)
    {
        int nl = t >> 3, j4 = t & 7;
        float4 vc = bc4[(b * Nn + n0 + nl) * 8 + j4];
        float4 vs = bs4[(b * Nn + n0 + nl) * 8 + j4];
        float* pc = ldc + nl * 33 + 4 * j4;
        pc[0] = vc.x; pc[1] = vc.y; pc[2] = vc.z; pc[3] = vc.w;
        float* ps = ldss + nl * 33 + 4 * j4;
        ps[0] = vs.x; ps[1] = vs.y; ps[2] = vs.z; ps[3] = vs.w;
        __syncthreads();
        int half = (t >> 2) & 1, u = t & 3;
        #pragma unroll
        for (int m = 0; m < 2; ++m) {
            const float* src = (half ? ldss : ldc) + nl * 33;
            float4 o;
            o.x = src[8 * u + m];     o.y = src[8 * u + 2 + m];
            o.z = src[8 * u + 4 + m]; o.w = src[8 * u + 6 + m];
            *(float4*)(pb + (((b * 2 + m) * Nn + n0 + nl) * 32) + half * 16 + 4 * u) = o;
        }
    }
    // phase B/D: grid-stride
    const int t0 = blk * 256 + t, S = 2500 * 256;
    for (int i = t0; i < Bb * Nn * CIN / 4; i += S) f_out4[i] = make_float4(0, 0, 0, 0);
    for (int i = t0; i < Bb * Nn; i += S) {
        float2 nd = ((const float2*)nodes)[i];
        float2 nv = ((const float2*)nrm)[i];
        pn[i] = make_float4(nd.x, nd.y, nv.x, nv.y);
    }
}

// ---------------- kernel 2: edge scatter, MFMA matvec, dedup'd staging
// wave owns 64 instances/super-iter: phase1 lane=instance geometry (4 VMEM),
// then 4 MFMA tiles of 16 with LDS-staged pb rows + fT rows.
// (b,m) = blockIdx&7 -> XCD-binned L2 working set.
__global__ __launch_bounds__(256, 4) void edge_kernel(
    const float4* __restrict__ pb4,
    const float4* __restrict__ pn,
    const float4* __restrict__ fT4,
    const int4* __restrict__ de4,
    const float* __restrict__ nwt,
    const float* __restrict__ wc,
    const float* __restrict__ wsp,
    const float* __restrict__ w0,
    float* __restrict__ f_out) {
    __shared__ __align__(16) float spb[4][16 * 68];   // [t32|s32|pad4] per inst
    __shared__ float sfs[4][16 * 33];
    const int t  = threadIdx.x;
    const int wv = t >> 6;
    const int l  = t & 63;
    const int c  = l & 15;
    const int q  = l >> 4;
    const int kb = (q & 1) * 8;
    const int mode = q >> 1;
    const unsigned smask = mode ? 0x80000000u : 0u;
    const int bm = blockIdx.x & 7;
    const int b  = bm >> 1, m = bm & 1;
    const int wid = (blockIdx.x >> 3) * 4 + wv;       // 0..1023

    // loop-invariant B fragments (weights, bf16): B[k=q*8+j][ch]
    short8 bf0, bf1;
    #pragma unroll
    for (int j = 0; j < 8; ++j) {
        int k = q * 8 + j;
        float w0v, w1v;
        if (k < 16) {
            w0v = 2.0f * wc[(c * Kk + k) * Mm + m];
            w1v = 2.0f * wc[((c + 16) * Kk + k) * Mm + m];
        } else {
            w0v = 2.0f * wsp[(c * Kk + (k - 16)) * Mm + m];
            w1v = 2.0f * wsp[((c + 16) * Kk + (k - 16)) * Mm + m];
        }
        bf0[j] = (short)f2bf(w0v);
        bf1[j] = (short)f2bf(w1v);
    }
    const float acc00 = w0[c * Mm + m] + 1.0f;
    const float acc01 = w0[(c + 16) * Mm + m] + 1.0f;

    float* myld = spb[wv];
    float* myfs = sfs[wv];
    const int il  = l >> 2, jj4 = l & 3;   // pb staging roles
    const int il8 = l >> 3, j8  = l & 7;   // fT staging roles

    for (int s = wid; s < EPB; s += WPB) {
        // phase 1: geometry, lane = instance
        int e = s * 64 + l;
        int4 d4 = de4[b * Ee + e];              // (t_m0,t_m1,s_m0,s_m1)
        int tn = m ? d4.y : d4.x;
        int sn = m ? d4.w : d4.z;
        int bt = b * Nn + tn;
        int bs = b * Nn + sn;
        float4 qt = pn[bt];
        float4 qs = pn[bs];
        float dx = qt.x - qs.x, dy = qt.y - qs.y;
        float r2 = dx * dx + dy * dy + 1e-6f;
        float scale = nwt[(b * Ee + e) * Mm + m] * (dx * qs.z + dy * qs.w) / r2;
        int pT = (bm * Nn + tn) * 8;            // float4 row bases
        int pS = (bm * Nn + sn) * 8;
        int pF = bs * 8;

        #pragma unroll 1
        for (int tau = 0; tau < 4; ++tau) {
            asm volatile("" ::: "memory");      // keep tile phases ordered
            // stage pb rows (16 inst x [t|s]), zero redundancy
            int srcA = tau * 16 + il;
            int pTa = __shfl(pT, srcA);
            int pSa = __shfl(pS, srcA);
            float4 v0 = pb4[pTa + jj4];
            float4 v1 = pb4[pTa + 4 + jj4];
            float4 v2 = pb4[pSa + jj4];
            float4 v3 = pb4[pSa + 4 + jj4];
            float* row = myld + il * 68;
            *(float4*)(row + 4 * jj4)      = v0;
            *(float4*)(row + 16 + 4 * jj4) = v1;
            *(float4*)(row + 32 + 4 * jj4) = v2;
            *(float4*)(row + 48 + 4 * jj4) = v3;
            // stage fT source rows (16 inst x 32ch), 16B/lane
            #pragma unroll
            for (int p = 0; p < 2; ++p) {
                int ilf = p * 8 + il8;
                int pFa = __shfl(pF, tau * 16 + ilf);
                float4 w4 = fT4[pFa + j8];
                float* fr = myfs + ilf * 33 + 4 * j8;
                fr[0] = w4.x; fr[1] = w4.y; fr[2] = w4.z; fr[3] = w4.w;
            }
            asm volatile("s_waitcnt lgkmcnt(0)" ::: "memory");

            // A-frag from LDS (same math as verified R3)
            const float* rr = myld + c * 68;
            float bct[8], bst[8], xx[8], yy[8];
            *(float4*)(bct)     = *(const float4*)(rr + kb);
            *(float4*)(bct + 4) = *(const float4*)(rr + kb + 4);
            *(float4*)(bst)     = *(const float4*)(rr + 16 + kb);
            *(float4*)(bst + 4) = *(const float4*)(rr + 16 + kb + 4);
            const float* sx = rr + 32 + (mode ? 16 : 0) + kb;
            const float* sy = rr + 32 + (mode ? 0 : 16) + kb;
            *(float4*)(xx)     = *(const float4*)(sx);
            *(float4*)(xx + 4) = *(const float4*)(sx + 4);
            *(float4*)(yy)     = *(const float4*)(sy);
            *(float4*)(yy + 4) = *(const float4*)(sy + 4);

            union { short8 s8; unsigned u[4]; } af;
            #pragma unroll
            for (int jp = 0; jp < 4; ++jp) {
                float s0 = __uint_as_float(__float_as_uint(bst[2 * jp])     ^ smask);
                float s1 = __uint_as_float(__float_as_uint(bst[2 * jp + 1]) ^ smask);
                float v0f = fmaf(bct[2 * jp],     xx[2 * jp],     s0 * yy[2 * jp]);
                float v1f = fmaf(bct[2 * jp + 1], xx[2 * jp + 1], s1 * yy[2 * jp + 1]);
                af.u[jp] = f2bf(v0f) | ((__float_as_uint(v1f) + 0x8000u) & 0xffff0000u);
            }
            f32x4 zero = {0.f, 0.f, 0.f, 0.f};
            f32x4 d0 = __builtin_amdgcn_mfma_f32_16x16x32_bf16(af.s8, bf0, zero, 0, 0, 0);
            f32x4 d1 = __builtin_amdgcn_mfma_f32_16x16x32_bf16(af.s8, bf1, zero, 0, 0, 0);

            // epilogue: lane holds (inst = 4q+r, ch = c / c+16)
            #pragma unroll
            for (int r = 0; r < 4; ++r) {
                int srcl = tau * 16 + 4 * q + r;
                float sc  = __shfl(scale, srcl);
                int   btr = __shfl(bt, srcl);
                float fs0 = myfs[(4 * q + r) * 33 + c];
                float fs1 = myfs[(4 * q + r) * 33 + c + 16];
                unsafeAtomicAdd(&f_out[btr * CIN + c],      (acc00 + d0[r]) * fs0 * sc);
                unsafeAtomicAdd(&f_out[btr * CIN + c + 16], (acc01 + d1[r]) * fs1 * sc);
            }
        }
    }
}

// ---------------- kernel 3: out[b,o,n] = bias[o] + sum_i wk[o,i] * f_out[b,n,i]
__global__ __launch_bounds__(256) void out_kernel(
    const float4* __restrict__ f_out4,
    const float* __restrict__ wk,
    const float* __restrict__ bias,
    float* __restrict__ out) {
    __shared__ float lwk[1024];
    __shared__ float lf[64 * 33];
    int blk  = blockIdx.x;
    int b    = blk / 313;
    int tile = blk % 313;
    int n0   = tile * 64;
    int t    = threadIdx.x;
    #pragma unroll
    for (int r = 0; r < 4; ++r) lwk[r * 256 + t] = wk[r * 256 + t];
    #pragma unroll
    for (int r = 0; r < 2; ++r) {
        int flat = r * 256 + t;           // 0..511
        int nl = flat >> 3, i4 = flat & 7;
        int n  = n0 + nl;
        float4 v = (n < Nn) ? f_out4[(b * Nn + n) * 8 + i4] : make_float4(0, 0, 0, 0);
        float* p = lf + nl * 33 + 4 * i4;
        p[0] = v.x; p[1] = v.y; p[2] = v.z; p[3] = v.w;
    }
    __syncthreads();
    int nl = t & 63;
    int og = t >> 6;
    int n  = n0 + nl;
    if (n < Nn) {
        #pragma unroll
        for (int r = 0; r < 8; ++r) {
            int o = r * 4 + og;
            float acc = bias[o];
            #pragma unroll
            for (int i = 0; i < 32; ++i) acc += lwk[o * 32 + i] * lf[nl * 33 + i];
            out[(b * COUT + o) * Nn + n] = acc;
        }
    }
}

extern "C" void kernel_launch(void* const* d_in, const int* in_sizes, int n_in,
                              void* d_out, int out_size, void* d_ws, size_t ws_size,
                              hipStream_t stream) {
    const float* f       = (const float*)d_in[0];
    const float* bases_c = (const float*)d_in[1];
    const float* bases_s = (const float*)d_in[2];
    const float* nodes   = (const float*)d_in[4];
    const float* nrm     = (const float*)d_in[5];
    const int*   de      = (const int*)d_in[6];
    const float* nwt     = (const float*)d_in[7];
    const float* wc      = (const float*)d_in[8];
    const float* wsp     = (const float*)d_in[9];
    const float* w0      = (const float*)d_in[10];
    const float* wk      = (const float*)d_in[11];
    const float* bias    = (const float*)d_in[12];
    float* out = (float*)d_out;

    float*  fT    = (float*)d_ws;                              // 2.56M floats
    float*  f_out = fT + (size_t)Bb * Nn * CIN;                // 2.56M floats
    float*  pb    = f_out + (size_t)Bb * Nn * CIN;             // 5.12M floats
    float4* pn    = (float4*)(pb + (size_t)Bb * Mm * Nn * 32); // 80k float4

    prep_fused<<<Bb * 625, 256, 0, stream>>>(f, (const float4*)bases_c,
                                             (const float4*)bases_s, nodes, nrm,
                                             fT, (float4*)f_out, pb, pn);
    edge_kernel<<<2048, 256, 0, stream>>>((const float4*)pb, pn, (const float4*)fT,
                                          (const int4*)de, nwt, wc, wsp, w0, f_out);
    out_kernel<<<Bb * 313, 256, 0, stream>>>((const float4*)f_out, wk, bias, out);
}

// Round 5
// 392.589 us; speedup vs baseline: 1.6641x; 1.0031x over previous
//
#include <hip/hip_runtime.h>

#define Bb 4
#define Nn 20000
#define Ee 320000
#define CIN 32
#define COUT 32
#define Kk 16
#define Mm 2
#define EPB (Ee / 64)   /* 5000 super-iters (64 instances) per (b,m) slice */
#define WPB 1024        /* waves per (b,m): (2048/8) blocks * 4 waves */

typedef __attribute__((ext_vector_type(8))) short short8;
typedef __attribute__((ext_vector_type(4))) float f32x4;

__device__ __forceinline__ unsigned f2bf(float x) {   // round-half-up bf16 bits
    union { float f; unsigned u; } c; c.f = x;
    return (c.u + 0x8000u) >> 16;
}

// ---------------- kernel 1: fused prep (unchanged from R4)
__global__ __launch_bounds__(256) void prep_fused(
    const float* __restrict__ f,
    const float4* __restrict__ bc4,
    const float4* __restrict__ bs4,
    const float* __restrict__ nodes,
    const float* __restrict__ nrm,
    float* __restrict__ fT,
    float4* __restrict__ f_out4,
    float* __restrict__ pb,
    float4* __restrict__ pn) {
    __shared__ float ldsT[32 * 33];
    __shared__ float ldc[32 * 33];
    __shared__ float ldss[32 * 33];
    const int t   = threadIdx.x;
    const int blk = blockIdx.x;            // 2500 blocks
    const int b   = blk / 625;
    const int n0  = (blk % 625) * 32;
    {
        int lane = t & 31, grp = t >> 5;
        #pragma unroll
        for (int r = 0; r < 4; ++r)
            ldsT[(grp + r * 8) * 33 + lane] = f[(b * CIN + grp + r * 8) * Nn + n0 + lane];
        __syncthreads();
        #pragma unroll
        for (int r = 0; r < 4; ++r)
            fT[(b * Nn + n0 + grp + r * 8) * CIN + lane] = ldsT[lane * 33 + grp + r * 8];
    }
    {
        int nl = t >> 3, j4 = t & 7;
        float4 vc = bc4[(b * Nn + n0 + nl) * 8 + j4];
        float4 vs = bs4[(b * Nn + n0 + nl) * 8 + j4];
        float* pc = ldc + nl * 33 + 4 * j4;
        pc[0] = vc.x; pc[1] = vc.y; pc[2] = vc.z; pc[3] = vc.w;
        float* ps = ldss + nl * 33 + 4 * j4;
        ps[0] = vs.x; ps[1] = vs.y; ps[2] = vs.z; ps[3] = vs.w;
        __syncthreads();
        int half = (t >> 2) & 1, u = t & 3;
        #pragma unroll
        for (int m = 0; m < 2; ++m) {
            const float* src = (half ? ldss : ldc) + nl * 33;
            float4 o;
            o.x = src[8 * u + m];     o.y = src[8 * u + 2 + m];
            o.z = src[8 * u + 4 + m]; o.w = src[8 * u + 6 + m];
            *(float4*)(pb + (((b * 2 + m) * Nn + n0 + nl) * 32) + half * 16 + 4 * u) = o;
        }
    }
    const int t0 = blk * 256 + t, S = 2500 * 256;
    for (int i = t0; i < Bb * Nn * CIN / 4; i += S) f_out4[i] = make_float4(0, 0, 0, 0);
    for (int i = t0; i < Bb * Nn; i += S) {
        float2 nd = ((const float2*)nodes)[i];
        float2 nv = ((const float2*)nrm)[i];
        pn[i] = make_float4(nd.x, nd.y, nv.x, nv.y);
    }
}

// ---------------- kernel 2: edge scatter, MFMA matvec, software-pipelined
// Steady state per tau: one s_waitcnt vmcnt(~8) at ds_write; atomics of tau-1
// and gathers of tau are the only outstanding VMEM; atomics never drained.
__global__ __launch_bounds__(256, 4) void edge_kernel(
    const float4* __restrict__ pb4,
    const float4* __restrict__ pn,
    const float* __restrict__ fT,
    const int4* __restrict__ de4,
    const float* __restrict__ nwt,
    const float* __restrict__ wc,
    const float* __restrict__ wsp,
    const float* __restrict__ w0,
    float* __restrict__ f_out) {
    __shared__ __align__(16) float spb[4][16 * 68];   // 17408 B
    const int t  = threadIdx.x;
    const int wv = t >> 6;
    const int l  = t & 63;
    const int c  = l & 15;
    const int q  = l >> 4;
    const int kb = (q & 1) * 8;
    const int mode = q >> 1;
    const unsigned smask = mode ? 0x80000000u : 0u;
    const int bm = blockIdx.x & 7;
    const int b  = bm >> 1, m = bm & 1;
    const int wid = (blockIdx.x >> 3) * 4 + wv;       // 0..1023
    const int rowoff = (b + m) * Nn;                  // bt -> pb row base add

    // loop-invariant B fragments (weights, bf16): B[k=q*8+j][ch]
    short8 bf0, bf1;
    #pragma unroll
    for (int j = 0; j < 8; ++j) {
        int k = q * 8 + j;
        float w0v, w1v;
        if (k < 16) {
            w0v = 2.0f * wc[(c * Kk + k) * Mm + m];
            w1v = 2.0f * wc[((c + 16) * Kk + k) * Mm + m];
        } else {
            w0v = 2.0f * wsp[(c * Kk + (k - 16)) * Mm + m];
            w1v = 2.0f * wsp[((c + 16) * Kk + (k - 16)) * Mm + m];
        }
        bf0[j] = (short)f2bf(w0v);
        bf1[j] = (short)f2bf(w1v);
    }
    const float acc00 = w0[c * Mm + m] + 1.0f;
    const float acc01 = w0[(c + 16) * Mm + m] + 1.0f;

    float* myld = spb[wv];
    const int il = l >> 2, jj4 = l & 3;

    // pipeline state
    float scale; int bt, bs;                 // current super-iter geometry
    float4 g0, g1, g2, g3;                   // prefetched pb rows (next tile)
    float fa[4], fb[4];                      // prefetched fs (next tile)
    int4  d4n;                               // geometry pipeline (next s)
    int   btn, bsn;
    float dxn, dyn, nzn, nwn2, nwn;

    // prologue: geometry for s0 (immediate) + prefetch tile (s0, tau 0)
    int s = wid;
    {
        int e = s * 64 + l;
        int4 d4 = de4[b * Ee + e];
        int tn = m ? d4.y : d4.x;
        int sn = m ? d4.w : d4.z;
        bt = b * Nn + tn;
        bs = b * Nn + sn;
        float4 qt = pn[bt];
        float4 qs = pn[bs];
        float dx = qt.x - qs.x, dy = qt.y - qs.y;
        float r2 = dx * dx + dy * dy + 1e-6f;
        scale = nwt[(b * Ee + e) * Mm + m] * (dx * qs.z + dy * qs.w) / r2;
        // prefetch tile 0
        int bta = __shfl(bt, il), bsa = __shfl(bs, il);
        int pTa = (bta + rowoff) * 8, pSa = (bsa + rowoff) * 8;
        g0 = pb4[pTa + jj4];     g1 = pb4[pTa + 4 + jj4];
        g2 = pb4[pSa + jj4];     g3 = pb4[pSa + 4 + jj4];
        #pragma unroll
        for (int r = 0; r < 4; ++r) {
            int bsr = __shfl(bs, 4 * q + r);
            fa[r] = fT[bsr * CIN + c];
            fb[r] = fT[bsr * CIN + c + 16];
        }
    }

    for (; s < EPB; s += WPB) {
        const bool last = (s + WPB >= EPB);
        #pragma unroll
        for (int tau = 0; tau < 4; ++tau) {
            // ---- 1. commit prefetched pb rows to LDS (wait = vmcnt(~8))
            float* row = myld + il * 68;
            *(float4*)(row + 4 * jj4)      = g0;
            *(float4*)(row + 16 + 4 * jj4) = g1;
            *(float4*)(row + 32 + 4 * jj4) = g2;
            *(float4*)(row + 48 + 4 * jj4) = g3;

            // ---- 2. A-frag read + pack + MFMA (verified numerics from R3/R4)
            const float* rr = myld + c * 68;
            float bct[8], bst[8], xx[8], yy[8];
            *(float4*)(bct)     = *(const float4*)(rr + kb);
            *(float4*)(bct + 4) = *(const float4*)(rr + kb + 4);
            *(float4*)(bst)     = *(const float4*)(rr + 16 + kb);
            *(float4*)(bst + 4) = *(const float4*)(rr + 16 + kb + 4);
            const float* sx = rr + 32 + (mode ? 16 : 0) + kb;
            const float* sy = rr + 32 + (mode ? 0 : 16) + kb;
            *(float4*)(xx)     = *(const float4*)(sx);
            *(float4*)(xx + 4) = *(const float4*)(sx + 4);
            *(float4*)(yy)     = *(const float4*)(sy);
            *(float4*)(yy + 4) = *(const float4*)(sy + 4);

            union { short8 s8; unsigned u[4]; } af;
            #pragma unroll
            for (int jp = 0; jp < 4; ++jp) {
                float s0 = __uint_as_float(__float_as_uint(bst[2 * jp])     ^ smask);
                float s1 = __uint_as_float(__float_as_uint(bst[2 * jp + 1]) ^ smask);
                float v0f = fmaf(bct[2 * jp],     xx[2 * jp],     s0 * yy[2 * jp]);
                float v1f = fmaf(bct[2 * jp + 1], xx[2 * jp + 1], s1 * yy[2 * jp + 1]);
                af.u[jp] = f2bf(v0f) | ((__float_as_uint(v1f) + 0x8000u) & 0xffff0000u);
            }
            f32x4 zero = {0.f, 0.f, 0.f, 0.f};
            f32x4 d0 = __builtin_amdgcn_mfma_f32_16x16x32_bf16(af.s8, bf0, zero, 0, 0, 0);
            f32x4 d1 = __builtin_amdgcn_mfma_f32_16x16x32_bf16(af.s8, bf1, zero, 0, 0, 0);

            // ---- 3. epilogue values (consume fs BEFORE prefetch overwrites)
            float val0[4], val1[4];
            int   btr[4];
            #pragma unroll
            for (int r = 0; r < 4; ++r) {
                int srcl = tau * 16 + 4 * q + r;
                float sc = __shfl(scale, srcl);
                btr[r]   = __shfl(bt, srcl);
                val0[r] = (acc00 + d0[r]) * fa[r] * sc;
                val1[r] = (acc01 + d1[r]) * fb[r] * sc;
            }

            // ---- 4. geometry pipeline for next super-iter
            if (tau == 1 && !last)
                d4n = de4[b * Ee + (s + WPB) * 64 + l];
            if (tau == 2 && !last) {
                int tn = m ? d4n.y : d4n.x;
                int sn = m ? d4n.w : d4n.z;
                btn = b * Nn + tn;
                bsn = b * Nn + sn;
                float4 qt = pn[btn];
                float4 qs = pn[bsn];
                dxn = qt.x - qs.x; dyn = qt.y - qs.y;
                nzn = qs.z; nwn2 = qs.w;
                nwn = nwt[(b * Ee + (s + WPB) * 64 + l) * Mm + m];
            }

            // ---- 5. prefetch next tile (pb rows + fs) BEFORE atomics
            if (tau < 3 || !last) {
                int ntau;
                if (tau == 3) {   // roll to next super-iter
                    float r2 = dxn * dxn + dyn * dyn + 1e-6f;
                    scale = nwn * (dxn * nzn + dyn * nwn2) / r2;
                    bt = btn; bs = bsn;
                    ntau = 0;
                } else {
                    ntau = tau + 1;
                }
                int srcA = ntau * 16 + il;
                int bta = __shfl(bt, srcA), bsa = __shfl(bs, srcA);
                int pTa = (bta + rowoff) * 8, pSa = (bsa + rowoff) * 8;
                g0 = pb4[pTa + jj4];     g1 = pb4[pTa + 4 + jj4];
                g2 = pb4[pSa + jj4];     g3 = pb4[pSa + 4 + jj4];
                #pragma unroll
                for (int r = 0; r < 4; ++r) {
                    int bsr = __shfl(bs, ntau * 16 + 4 * q + r);
                    fa[r] = fT[bsr * CIN + c];
                    fb[r] = fT[bsr * CIN + c + 16];
                }
            }

            // ---- 6. atomics last; nothing may cross this point
            __builtin_amdgcn_sched_barrier(0);
            #pragma unroll
            for (int r = 0; r < 4; ++r) {
                unsafeAtomicAdd(&f_out[btr[r] * CIN + c],      val0[r]);
                unsafeAtomicAdd(&f_out[btr[r] * CIN + c + 16], val1[r]);
            }
        }
    }
}

// ---------------- kernel 3: out[b,o,n] = bias[o] + sum_i wk[o,i] * f_out[b,n,i]
__global__ __launch_bounds__(256) void out_kernel(
    const float4* __restrict__ f_out4,
    const float* __restrict__ wk,
    const float* __restrict__ bias,
    float* __restrict__ out) {
    __shared__ float lwk[1024];
    __shared__ float lf[64 * 33];
    int blk  = blockIdx.x;
    int b    = blk / 313;
    int tile = blk % 313;
    int n0   = tile * 64;
    int t    = threadIdx.x;
    #pragma unroll
    for (int r = 0; r < 4; ++r) lwk[r * 256 + t] = wk[r * 256 + t];
    #pragma unroll
    for (int r = 0; r < 2; ++r) {
        int flat = r * 256 + t;
        int nl = flat >> 3, i4 = flat & 7;
        int n  = n0 + nl;
        float4 v = (n < Nn) ? f_out4[(b * Nn + n) * 8 + i4] : make_float4(0, 0, 0, 0);
        float* p = lf + nl * 33 + 4 * i4;
        p[0] = v.x; p[1] = v.y; p[2] = v.z; p[3] = v.w;
    }
    __syncthreads();
    int nl = t & 63;
    int og = t >> 6;
    int n  = n0 + nl;
    if (n < Nn) {
        #pragma unroll
        for (int r = 0; r < 8; ++r) {
            int o = r * 4 + og;
            float acc = bias[o];
            #pragma unroll
            for (int i = 0; i < 32; ++i) acc += lwk[o * 32 + i] * lf[nl * 33 + i];
            out[(b * COUT + o) * Nn + n] = acc;
        }
    }
}

extern "C" void kernel_launch(void* const* d_in, const int* in_sizes, int n_in,
                              void* d_out, int out_size, void* d_ws, size_t ws_size,
                              hipStream_t stream) {
    const float* f       = (const float*)d_in[0];
    const float* bases_c = (const float*)d_in[1];
    const float* bases_s = (const float*)d_in[2];
    const float* nodes   = (const float*)d_in[4];
    const float* nrm     = (const float*)d_in[5];
    const int*   de      = (const int*)d_in[6];
    const float* nwt     = (const float*)d_in[7];
    const float* wc      = (const float*)d_in[8];
    const float* wsp     = (const float*)d_in[9];
    const float* w0      = (const float*)d_in[10];
    const float* wk      = (const float*)d_in[11];
    const float* bias    = (const float*)d_in[12];
    float* out = (float*)d_out;

    float*  fT    = (float*)d_ws;                              // 2.56M floats
    float*  f_out = fT + (size_t)Bb * Nn * CIN;                // 2.56M floats
    float*  pb    = f_out + (size_t)Bb * Nn * CIN;             // 5.12M floats
    float4* pn    = (float4*)(pb + (size_t)Bb * Mm * Nn * 32); // 80k float4

    prep_fused<<<Bb * 625, 256, 0, stream>>>(f, (const float4*)bases_c,
                                             (const float4*)bases_s, nodes, nrm,
                                             fT, (float4*)f_out, pb, pn);
    edge_kernel<<<2048, 256, 0, stream>>>((const float4*)pb, pn, fT,
                                          (const int4*)de, nwt, wc, wsp, w0, f_out);
    out_kernel<<<Bb * 313, 256, 0, stream>>>((const float4*)f_out, wk, bias, out);
}